// Round 4
// baseline (382.414 us; speedup 1.0000x reference)
//
#include <hip/hip_runtime.h>
#include <cstdint>

// Problem: M=16384, K=2048, N=2048 fp8(e4m3) delayed-scaling dense fwd.
#define M_DIM 16384
#define K_DIM 2048
#define N_DIM 2048

typedef float f32x4 __attribute__((ext_vector_type(4)));
typedef int   i32x8 __attribute__((ext_vector_type(8)));

// ---------------------------------------------------------------------------
// Kernel 1: quantize x [M,K] f32 -> fp8 e4m3 (RNE via v_cvt_pk_fp8_f32),
// fused amax. Grid-stride float4 loads: 64 lanes x 16B consecutive = 1KB/instr.
// ---------------------------------------------------------------------------
__global__ __launch_bounds__(256) void quant_x_kernel(
    const float4* __restrict__ x, uint4* __restrict__ xq,
    const float* __restrict__ scale, unsigned int* __restrict__ amax)
{
    const int gid = blockIdx.x * 256 + threadIdx.x;   // 4096*256 = 1048576 threads
    const float s = scale[0];
    float m = 0.0f;
#pragma unroll
    for (int j = 0; j < 8; ++j) {
        float4 v = x[gid + j * 1048576];
        m = fmaxf(m, fmaxf(fmaxf(fabsf(v.x), fabsf(v.y)),
                           fmaxf(fabsf(v.z), fabsf(v.w))));
        unsigned int p0 = __builtin_amdgcn_cvt_pk_fp8_f32(v.x * s, v.y * s, 0, false);
        unsigned int p  = __builtin_amdgcn_cvt_pk_fp8_f32(v.z * s, v.w * s, p0, true);
        ((unsigned int*)xq)[gid + j * 1048576] = p;   // 4 fp8 per dword, coalesced
    }

#pragma unroll
    for (int off = 32; off > 0; off >>= 1)
        m = fmaxf(m, __shfl_down(m, off, 64));
    __shared__ float red[4];
    if ((threadIdx.x & 63) == 0) red[threadIdx.x >> 6] = m;
    __syncthreads();
    if (threadIdx.x == 0) {
        m = fmaxf(fmaxf(red[0], red[1]), fmaxf(red[2], red[3]));
        atomicMax(amax, __float_as_uint(m));  // values >= 0: uint order == float order
    }
}

// ---------------------------------------------------------------------------
// Kernel 2: quantize + transpose kernel [K,N] f32 -> wq [N,K] fp8, fused amax.
// ---------------------------------------------------------------------------
__global__ __launch_bounds__(256) void quant_w_kernel(
    const float* __restrict__ w, uint8_t* __restrict__ wq,
    const float* __restrict__ scale, unsigned int* __restrict__ amax)
{
    __shared__ float tile[64][68];
    const int t = threadIdx.x;
    const int nb = blockIdx.x * 64;
    const int kb = blockIdx.y * 64;
    const float s = scale[1];
    float m = 0.0f;
#pragma unroll
    for (int j = 0; j < 4; ++j) {
        int f = j * 256 + t;
        int row = f >> 4;
        int c4 = f & 15;
        float4 v = *(const float4*)(w + (size_t)(kb + row) * N_DIM + nb + c4 * 4);
        m = fmaxf(m, fmaxf(fmaxf(fabsf(v.x), fabsf(v.y)),
                           fmaxf(fabsf(v.z), fabsf(v.w))));
        *(float4*)(&tile[row][c4 * 4]) = v;
    }
    __syncthreads();
    const int n = t >> 2, c = t & 3;
    unsigned int pk[4];
#pragma unroll
    for (int jj = 0; jj < 4; ++jj) {
        float f0 = tile[c * 16 + jj * 4 + 0][n] * s;
        float f1 = tile[c * 16 + jj * 4 + 1][n] * s;
        float f2 = tile[c * 16 + jj * 4 + 2][n] * s;
        float f3 = tile[c * 16 + jj * 4 + 3][n] * s;
        unsigned int p = __builtin_amdgcn_cvt_pk_fp8_f32(f0, f1, 0, false);
        pk[jj] = __builtin_amdgcn_cvt_pk_fp8_f32(f2, f3, p, true);
    }
    *(uint4*)(wq + (size_t)(nb + n) * K_DIM + kb + c * 16) = make_uint4(pk[0], pk[1], pk[2], pk[3]);

#pragma unroll
    for (int off = 32; off > 0; off >>= 1)
        m = fmaxf(m, __shfl_down(m, off, 64));
    __shared__ float red[4];
    if ((t & 63) == 0) red[t >> 6] = m;
    __syncthreads();
    if (t == 0) {
        m = fmaxf(fmaxf(red[0], red[1]), fmaxf(red[2], red[3]));
        atomicMax(amax, __float_as_uint(m));
    }
}

// ---------------------------------------------------------------------------
// Kernel 3: MX-scaled fp8 GEMM, software-pipelined (depth 1).
// C[m,n] = sum_k Aq[m,k]*Bq[n,k];  mfma_scale_f32_16x16x128_f8f6f4, scales=1.0.
//
// LDS (64 KB exactly = 2 buffers x (A 16KB + B 16KB), no pads):
//   Per matrix, 8 row-groups of 16 rows. Group g = two 1KB segments:
//     seg 2g   : every lane's k-half0 16B at  g*2048 +        lane*16
//     seg 2g+1 : every lane's k-half1 16B at  g*2048 + 1024 + lane*16
//   Both staging writes AND fragment reads are lane-linear 16B stride ->
//   8-phase structural minimum, no pads needed.
// Pipeline: issue tile kt+1's global_load_lds right AFTER the barrier that
// publishes tile kt, then compute kt. The vmcnt(0) inside the next
// __syncthreads() waits on loads that are a full compute phase old.
// One barrier per kt.
// ---------------------------------------------------------------------------
__global__ __launch_bounds__(256) void gemm_fp8_kernel(
    const uint8_t* __restrict__ Aq, const uint8_t* __restrict__ Bq,
    const float* __restrict__ scale, float* __restrict__ C)
{
    __shared__ uint8_t lds[65536];   // [buf:2][mat:2][16KB]
    const int tid  = threadIdx.x;
    const int wave = tid >> 6;
    const int lane = tid & 63;
    const int wm = wave >> 1, wn = wave & 1;   // 2x2 wave grid, 64x64 per wave
    const int q = lane >> 4, r = lane & 15;

    // XCD-aware swizzle: XCD x owns bm in [x*16, x*16+16) (A stripe ~4MB in L2),
    // bn sweeps 0..15 within that. blk -> xcd round-robin is blk & 7.
    const int blk = blockIdx.x;
    const int xcd = blk & 7;
    const int idx = blk >> 3;                  // 0..255
    const int bm  = xcd * 16 + (idx >> 4);     // 0..127
    const int bn  = idx & 15;                  // 0..15

    const size_t a_base = (size_t)bm * 128 * K_DIM;
    const size_t b_base = (size_t)bn * 128 * K_DIM;

    // Staging geometry: wave handles segments s = j*4 + wave, s = 2g + h.
    // Staging lane sl of segment s fetches global row g*16 + (sl&15),
    // k-offset (sl>>4)*32 + h*16 -> lands at s*1024 + sl*16 (lane-linear).
    int srow[4], skoff[4], sdst[4];
#pragma unroll
    for (int j = 0; j < 4; ++j) {
        const int s = j * 4 + wave;
        srow[j]  = (s >> 1) * 16 + (lane & 15);
        skoff[j] = (lane >> 4) * 32 + (s & 1) * 16;
        sdst[j]  = s * 1024 + lane * 16;
    }

    f32x4 acc[4][4];
#pragma unroll
    for (int i = 0; i < 4; ++i)
#pragma unroll
        for (int j = 0; j < 4; ++j) acc[i][j] = (f32x4){0.f, 0.f, 0.f, 0.f};

    const int SONE = 0x7F7F7F7F;   // e8m0 scale = 1.0 in every byte

    // issue staging loads for tile kt into buffer b
    auto issue = [&](int kt, int b) {
        const size_t kg = (size_t)kt * 128;
        uint8_t* base = lds + b * 32768;
#pragma unroll
        for (int j = 0; j < 4; ++j) {
            const uint8_t* ga = Aq + a_base + (size_t)srow[j] * K_DIM + kg + skoff[j];
            const uint8_t* gb = Bq + b_base + (size_t)srow[j] * K_DIM + kg + skoff[j];
            __builtin_amdgcn_global_load_lds(
                (const __attribute__((address_space(1))) uint32_t*)ga,
                (__attribute__((address_space(3))) uint32_t*)(base + sdst[j]), 16, 0, 0);
            __builtin_amdgcn_global_load_lds(
                (const __attribute__((address_space(1))) uint32_t*)gb,
                (__attribute__((address_space(3))) uint32_t*)(base + 16384 + sdst[j]), 16, 0, 0);
        }
    };

    issue(0, 0);

    for (int kt = 0; kt < K_DIM / 128; ++kt) {
        __syncthreads();                 // vmcnt(0): tile kt ready (issued a phase ago)
        if (kt + 1 < K_DIM / 128) issue(kt + 1, (kt + 1) & 1);

        const uint8_t* base = lds + (kt & 1) * 32768;
        i32x8 a_frag[4], b_frag[4];
#pragma unroll
        for (int mi = 0; mi < 4; ++mi) {
            const uint8_t* pa = base + (wm * 4 + mi) * 2048 + lane * 16;
            int4 lo = *(const int4*)pa;
            int4 hi = *(const int4*)(pa + 1024);
            a_frag[mi] = (i32x8){lo.x, lo.y, lo.z, lo.w, hi.x, hi.y, hi.z, hi.w};
        }
#pragma unroll
        for (int ni = 0; ni < 4; ++ni) {
            const uint8_t* pb = base + 16384 + (wn * 4 + ni) * 2048 + lane * 16;
            int4 lo = *(const int4*)pb;
            int4 hi = *(const int4*)(pb + 1024);
            b_frag[ni] = (i32x8){lo.x, lo.y, lo.z, lo.w, hi.x, hi.y, hi.z, hi.w};
        }
#pragma unroll
        for (int mi = 0; mi < 4; ++mi)
#pragma unroll
            for (int ni = 0; ni < 4; ++ni)
                acc[mi][ni] = __builtin_amdgcn_mfma_scale_f32_16x16x128_f8f6f4(
                    a_frag[mi], b_frag[ni], acc[mi][ni],
                    0 /*cbsz: fp8*/, 0 /*blgp: fp8*/,
                    0, SONE, 0, SONE);
    }

    // epilogue: D col = lane&15, row = q*4 + reg (m89-verified, shape-determined)
    // nontemporal: C is write-once, keep it from evicting A in L2/L3.
    const float sinv = (1.0f / scale[0]) * (1.0f / scale[1]);
#pragma unroll
    for (int mi = 0; mi < 4; ++mi) {
#pragma unroll
        for (int ni = 0; ni < 4; ++ni) {
            const int col  = bn * 128 + wn * 64 + ni * 16 + r;
            const int row0 = bm * 128 + wm * 64 + mi * 16 + q * 4;
#pragma unroll
            for (int rr = 0; rr < 4; ++rr)
                __builtin_nontemporal_store(acc[mi][ni][rr] * sinv,
                    &C[(size_t)(row0 + rr) * N_DIM + col]);
        }
    }
}

// ---------------------------------------------------------------------------
// Kernel 4: scale update (faithful _sf_compute incl. tf.where ordering) +
// rolled amax history (always zeros for 1-row history).
// ---------------------------------------------------------------------------
__global__ void finalize_kernel(const float* __restrict__ scale,
                                const unsigned int* __restrict__ amax_bits,
                                float* __restrict__ out_tail)
{
    const int i = threadIdx.x;
    if (i < 2) {
        const float amax = __uint_as_float(amax_bits[i]);
        const float sc = scale[i];
        const float e = floorf(log2f(448.0f / amax));
        float sf = roundf(exp2f(fabsf(e)));
        sf = (amax > 0.0f) ? sf : sc;
        sf = isinf(amax) ? sf : sc;      // faithful: finite amax collapses to scale
        if (e < 0.0f) sf = 1.0f / sf;
        out_tail[i] = sf;                // new_scale
        out_tail[2 + i] = 0.0f;          // rolled history (single row -> zeros)
    }
}

// ---------------------------------------------------------------------------
extern "C" void kernel_launch(void* const* d_in, const int* in_sizes, int n_in,
                              void* d_out, int out_size, void* d_ws, size_t ws_size,
                              hipStream_t stream)
{
    const float* x     = (const float*)d_in[0];
    const float* w     = (const float*)d_in[1];
    const float* scale = (const float*)d_in[2];

    uint8_t* ws = (uint8_t*)d_ws;
    uint8_t* xq = ws;                                            // M*K fp8 (32 MB)
    uint8_t* wq = ws + (size_t)M_DIM * K_DIM;                    // N*K fp8 (4 MB)
    unsigned int* amax = (unsigned int*)(ws + (size_t)M_DIM * K_DIM + (size_t)N_DIM * K_DIM);

    hipMemsetAsync(amax, 0, 2 * sizeof(unsigned int), stream);

    quant_x_kernel<<<4096, 256, 0, stream>>>(
        (const float4*)x, (uint4*)xq, scale, amax);

    dim3 gw(N_DIM / 64, K_DIM / 64);
    quant_w_kernel<<<gw, 256, 0, stream>>>(w, wq, scale, amax + 1);

    gemm_fp8_kernel<<<2048, 256, 0, stream>>>(xq, wq, scale, (float*)d_out);

    finalize_kernel<<<1, 64, 0, stream>>>(scale, amax,
                                          (float*)d_out + (size_t)M_DIM * N_DIM);
}